// Round 5
// baseline (358.285 us; speedup 1.0000x reference)
//
#include <hip/hip_runtime.h>

// ---------------------------------------------------------------------------
// LiteMLA: B=4, N=4096, C=1024, D=32, h=32 heads.
//   qkv = x @ W_qkv^T            (16384 x 3072, K=1024)   [relu on q,k cols]
//   per (b,h): vk[d,e] = sum_n Vpad[d,n]*reluK[e,n]   (33x32, reduce N=4096)
//              y[d,n]  = (sum_e vk[d,e]*reluQ[e,n]) / (sum_e vk[32,e]*reluQ[e,n] + eps)
//   out = y @ W_proj^T + b_proj  (16384 x 1024, K=1024)
//
// GEMM (R5): 256x256 tile, BK=64, 8 waves (128x64/wave). LDS-pipe analysis of
// R1-R4 (all ~40% MfmaUtil): per tile LDS demand (A+B reads 192KB + DMA 64KB
// ~2900cyc) >= MFMA (~2486cyc) -> serialization wall. Fix: B (L2-hot weight
// panel) is loaded GLOBAL->REG (16x64B segments/instr), double-buffered one
// tile ahead (bA/bB). LDS carries only A (triple-buffered 3x32KB=96KB):
// reads 128KB + writes 32KB ~1700cyc < MFMA -> MFMA-bound ceiling.
// Schedule per tile (1 barrier + 1 counted vmcnt, FENCE-pinned issue order):
//   F1: read af M0 (8 ds_read) ; gather B(g+1)x8 ; MFMA M0 (32)
//   F2: stage A(g+2)x4 -> buf[(g+2)%3] ; read af M1 ; MFMA M1 (32)
//       vmcnt(12)  [retires A(g+1): newer = B(g+1)8 + A(g+2)4] ; s_barrier
// Triple-buffer => staged buffer is never concurrently read (reads of its
// previous content drained by the barrier one tile earlier). vmcnt never
// drains to 0 in-loop. Per-element accumulation order (g asc, kk asc)
// unchanged -> numerics identical to verified kernel.
// A LDS layout: [256 rows][64], slot swizzle (kk*4+kq)^(row&7) via
// pre-swizzled global source + XOR'd ds_read (R4-verified, 0 conflicts).
// ---------------------------------------------------------------------------

using us8   = __attribute__((ext_vector_type(8))) unsigned short;
using us4   = __attribute__((ext_vector_type(4))) unsigned short;
using s8v   = __attribute__((ext_vector_type(8))) short;
using f32x4 = __attribute__((ext_vector_type(4))) float;

__device__ __forceinline__ unsigned short f2bf(float f) {
    union { float f; unsigned int u; } c; c.f = f;
    unsigned int r = c.u + 0x7fffu + ((c.u >> 16) & 1u);   // RTN-even
    return (unsigned short)(r >> 16);
}
__device__ __forceinline__ float bf2f(unsigned short u) {
    union { unsigned int u; float f; } c; c.u = ((unsigned int)u) << 16;
    return c.f;
}

// async global->LDS, 16B per lane; LDS dest = wave-uniform base + lane*16
__device__ __forceinline__ void async16(const unsigned short* g, unsigned short* l) {
    __builtin_amdgcn_global_load_lds(
        (const __attribute__((address_space(1))) unsigned int*)g,
        (__attribute__((address_space(3))) unsigned int*)l, 16, 0, 0);
}

// ------------------ fused fp32->bf16 converts + vkws zero ------------------
__global__ __launch_bounds__(256)
void prep(const float* __restrict__ x, const float* __restrict__ wq,
          const float* __restrict__ wp, unsigned short* __restrict__ xb,
          unsigned short* __restrict__ wqb, unsigned short* __restrict__ wpb,
          float* __restrict__ vkws) {
    const int NX = 16777216 / 8, NQ = 3145728 / 8, NP = 1048576 / 8, NZ = 135168 / 8;
    int gid = blockIdx.x * 256 + threadIdx.x;
    const float* in; unsigned short* out; int i;
    if (gid < NX)                    { in = x;  out = xb;  i = gid * 8; }
    else if (gid < NX + NQ)          { in = wq; out = wqb; i = (gid - NX) * 8; }
    else if (gid < NX + NQ + NP)     { in = wp; out = wpb; i = (gid - NX - NQ) * 8; }
    else if (gid < NX + NQ + NP + NZ) {
        int z = (gid - NX - NQ - NP) * 8;
        f32x4 zero = {};
        *(f32x4*)(vkws + z) = zero; *(f32x4*)(vkws + z + 4) = zero;
        return;
    } else return;
    float4 a = *(const float4*)(in + i);
    float4 b = *(const float4*)(in + i + 4);
    us8 o;
    o[0] = f2bf(a.x); o[1] = f2bf(a.y); o[2] = f2bf(a.z); o[3] = f2bf(a.w);
    o[4] = f2bf(b.x); o[5] = f2bf(b.y); o[6] = f2bf(b.z); o[7] = f2bf(b.w);
    *(us8*)(out + i) = o;
}

// -------------------- 256x256 GEMM, B-in-registers core --------------------
#define FENCE() asm volatile("" ::: "memory")
#define BARX()  do { FENCE(); __builtin_amdgcn_s_barrier(); FENCE(); } while (0)

#define MFMA_H(AF, BF, MB)                                                   \
  do {                                                                       \
    __builtin_amdgcn_s_setprio(1);                                           \
    _Pragma("unroll")                                                        \
    for (int mi_ = 0; mi_ < 4; ++mi_)                                        \
      _Pragma("unroll")                                                      \
      for (int ni_ = 0; ni_ < 4; ++ni_)                                      \
        _Pragma("unroll")                                                    \
        for (int kk_ = 0; kk_ < 2; ++kk_)                                    \
          acc[(MB) + mi_][ni_] = __builtin_amdgcn_mfma_f32_16x16x32_bf16(    \
              AF[mi_][kk_], BF[ni_][kk_], acc[(MB) + mi_][ni_], 0, 0, 0);    \
    __builtin_amdgcn_s_setprio(0);                                           \
  } while (0)

// gather one K-tile of B frags for this wave's 64-col slab (L2-hot): 8 x
// global_load_dwordx4, each = 16 segments x 64B (4 kq-quads contiguous).
#define GATHERB(DST, KT)                                                     \
  do {                                                                       \
    _Pragma("unroll")                                                        \
    for (int ni_ = 0; ni_ < 4; ++ni_) {                                      \
      DST[ni_][0] = *(const s8v*)(Bgl + (size_t)ni_ * 16384 + (KT));         \
      DST[ni_][1] = *(const s8v*)(Bgl + (size_t)ni_ * 16384 + (KT) + 32);    \
    }                                                                        \
  } while (0)

// stage one 256x64 A-tile (32 KB) into an LDS buffer: 4 async16/thread,
// linear dest; global source pre-swizzled (esw, row-consistent across j).
#define STAGEA(KT, BUF)                                                      \
  do {                                                                       \
    _Pragma("unroll")                                                        \
    for (int j_ = 0; j_ < 4; ++j_)                                           \
      async16(Aglane + (size_t)j_ * 65536 + (KT),                            \
              (BUF) + j_ * 4096 + wv * 512);                                 \
  } while (0)

// One K-tile: F1 {read af M0, gather B(g+1)->BPRE, MFMA M0 w/ BUSE},
// F2 {stage A(g+2), read af M1, MFMA M1, vmcnt(12), barrier}.
#define TILEG(G, BUSE, BPRE)                                                 \
  do {                                                                       \
    unsigned short* bufR = lds + 16384 * ((G) % 3);                          \
    unsigned short* bufS = lds + 16384 * (((G) + 2) % 3);                    \
    const int ktB = ((G) + 1 < 16 ? (G) + 1 : 15) * 64;                      \
    const int ktA = ((G) + 2 < 16 ? (G) + 2 : 15) * 64;                      \
    _Pragma("unroll")                                                        \
    for (int mi_ = 0; mi_ < 4; ++mi_) {                                      \
      af[mi_][0] = *(const s8v*)&bufR[(wr * 128 + mi_ * 16 + mrow) * 64 + ks0]; \
      af[mi_][1] = *(const s8v*)&bufR[(wr * 128 + mi_ * 16 + mrow) * 64 + ks1]; \
    }                                                                        \
    GATHERB(BPRE, ktB);                                                      \
    FENCE();                                                                 \
    MFMA_H(af, BUSE, 0);                                                     \
    STAGEA(ktA, bufS);                                                       \
    FENCE();                                                                 \
    _Pragma("unroll")                                                        \
    for (int mi_ = 0; mi_ < 4; ++mi_) {                                      \
      af[mi_][0] = *(const s8v*)&bufR[(wr * 128 + 64 + mi_ * 16 + mrow) * 64 + ks0]; \
      af[mi_][1] = *(const s8v*)&bufR[(wr * 128 + 64 + mi_ * 16 + mrow) * 64 + ks1]; \
    }                                                                        \
    MFMA_H(af, BUSE, 4);                                                     \
    asm volatile("s_waitcnt vmcnt(12)" ::: "memory");                        \
    BARX();                                                                  \
  } while (0)

// MODE 0: cols<1024 -> Q token-major bf16 (relu); cols>=1024 -> kvT.
// MODE 1: fp32 + bias.
template <int MODE>
__device__ __forceinline__
void gemm_core256(const unsigned short* __restrict__ A,
                  const unsigned short* __restrict__ Bt,
                  unsigned short* __restrict__ Cq,
                  unsigned short* __restrict__ kvT,
                  float* __restrict__ Cf, const float* __restrict__ bias,
                  int N, int tM, int tN, unsigned short* lds) {
    const int t    = threadIdx.x;
    const int lane = t & 63;
    const int wv   = t >> 6;
    const int wr   = wv >> 2;                 // 0..1 : A 128-row slab
    const int wc   = wv & 3;                  // 0..3 : 64-col slab
    const int mrow = lane & 15;
    const int kq   = lane >> 4;               // 0..3
    const int m7   = lane & 7;

    // A staging thread map (rows row0 + j*64, pre-swizzled source element)
    const int row0 = t >> 3;
    const int esw  = ((t & 7) ^ (row0 & 7)) * 8;
    const unsigned short* Aglane = A + (size_t)(tM + row0) * 1024 + esw;

    // B gather base: this wave's col slab, this lane's (col,kq) slot
    const unsigned short* Bgl =
        Bt + (size_t)(tN + wc * 64 + mrow) * 1024 + kq * 8;

    // swizzled k-slot offsets for A ds_read (kk=0/1)
    const int ks0 = ((0 * 4 + kq) ^ m7) * 8;
    const int ks1 = ((1 * 4 + kq) ^ m7) * 8;

    f32x4 acc[8][4] = {};
    s8v af[4][2], bA[4][2], bB[4][2];

    // prologue: A(0)->buf0, A(1)->buf1, gather B(0).
    // issue order [A0 x4, A1 x4, B0 x8]; vmcnt(12) retires A(0).
    STAGEA(0, lds);
    STAGEA(64, lds + 16384);
    FENCE();
    GATHERB(bA, 0);
    asm volatile("s_waitcnt vmcnt(12)" ::: "memory");
    BARX();

#pragma unroll
    for (int g2 = 0; g2 < 8; ++g2) {
        TILEG(2 * g2,     bA, bB);
        TILEG(2 * g2 + 1, bB, bA);
    }

    // ----------------------------- epilogue --------------------------------
    const int crow0 = kq * 4;
    const int ccol  = mrow;
    if (MODE == 0) {
        if (tN >= 1024) {
            const int b2  = tM >> 12;
            const int nb0 = (tM & 4095) + wr * 128;
#pragma unroll
            for (int mi = 0; mi < 8; ++mi) {
                const int nbase = nb0 + mi * 16 + crow0;
#pragma unroll
                for (int ni = 0; ni < 4; ++ni) {
                    const int col = tN + wc * 64 + ni * 16 + ccol;
                    f32x4 v = acc[mi][ni];
                    if (col < 2048) {
                        v[0] = fmaxf(v[0], 0.f); v[1] = fmaxf(v[1], 0.f);
                        v[2] = fmaxf(v[2], 0.f); v[3] = fmaxf(v[3], 0.f);
                    }
                    us4 o;
                    o[0] = f2bf(v[0]); o[1] = f2bf(v[1]);
                    o[2] = f2bf(v[2]); o[3] = f2bf(v[3]);
                    *(us4*)&kvT[((size_t)b2 * 2048 + (col - 1024)) * 4096 + nbase] = o;
                }
            }
        } else {
#pragma unroll
            for (int mi = 0; mi < 8; ++mi)
#pragma unroll
                for (int ni = 0; ni < 4; ++ni) {
                    const int row = tM + wr * 128 + mi * 16 + crow0;
                    const int col = tN + wc * 64 + ni * 16 + ccol;
#pragma unroll
                    for (int r2 = 0; r2 < 4; ++r2)
                        Cq[(size_t)(row + r2) * 1024 + col] =
                            f2bf(fmaxf(acc[mi][ni][r2], 0.f));
                }
        }
    } else {
#pragma unroll
        for (int mi = 0; mi < 8; ++mi)
#pragma unroll
            for (int ni = 0; ni < 4; ++ni) {
                const int row = tM + wr * 128 + mi * 16 + crow0;
                const int col = tN + wc * 64 + ni * 16 + ccol;
#pragma unroll
                for (int r2 = 0; r2 < 4; ++r2)
                    Cf[(size_t)(row + r2) * N + col] = acc[mi][ni][r2] + bias[col];
            }
    }
    // drain LDS-DMA before wave exit (LDS may be re-allocated to next block)
    asm volatile("s_waitcnt vmcnt(0)" ::: "memory");
}

// XCD-aware tile map: xcd = blk&7 owns an 8-M-tile stripe; N swept in panels
// of 4 (B-panel 512KB..2MB stays L2-hot), tN fastest within panel.
__device__ __forceinline__ void xcd_map256(int blk, int MT, int& tM, int& tN) {
    const int xcd = blk & 7;
    const int i   = blk >> 3;
    const int MTx = MT >> 3;             // M-tiles per XCD (8)
    const int ppan = MTx * 4;            // blocks per 4-wide panel per XCD
    const int p   = i / ppan;
    const int i2  = i % ppan;
    tM = (xcd * MTx + (i2 >> 2)) * 256;
    tN = (p * 4 + (i2 & 3)) * 256;
}

__global__ __launch_bounds__(512, 2)
void gemm_qkv(const unsigned short* __restrict__ A,
              const unsigned short* __restrict__ Bt,
              unsigned short* __restrict__ Cq, unsigned short* __restrict__ kvT,
              int M, int N) {
    extern __shared__ unsigned short lds[];
    int tM, tN;
    xcd_map256(blockIdx.x, M >> 8, tM, tN);
    gemm_core256<0>(A, Bt, Cq, kvT, nullptr, nullptr, N, tM, tN, lds);
}

__global__ __launch_bounds__(512, 2)
void gemm_proj(const unsigned short* __restrict__ A,
               const unsigned short* __restrict__ Bt,
               float* __restrict__ C, const float* __restrict__ bias,
               int M, int N) {
    extern __shared__ unsigned short lds[];
    int tM, tN;
    xcd_map256(blockIdx.x, M >> 8, tM, tN);
    gemm_core256<1>(A, Bt, nullptr, nullptr, C, bias, N, tM, tN, lds);
}

// ---------------- vk = Vpad @ reluK^T via MFMA over kvT --------------------
__global__ __launch_bounds__(256)
void lite_vk(const unsigned short* __restrict__ kvT, float* __restrict__ vkws) {
    const int bh = blockIdx.x, ck = blockIdx.y;
    const int b = bh >> 5, h = bh & 31;
    const int S = 136;
    __shared__ unsigned short Ks[32 * S];
    __shared__ unsigned short Vs[32 * S];
    __shared__ float Rs[4][1088];
    const int t = threadIdx.x, lane = t & 63, wv = t >> 6;
    const unsigned short* Kp = kvT + ((size_t)b * 2048 + h * 32) * 4096 + ck * 512;
    const unsigned short* Vp = kvT + ((size_t)b * 2048 + 1024 + h * 32) * 4096 + ck * 512;
    const int sr = t >> 3, ss = (t & 7) * 16;
    f32x4 acc00 = {}, acc01 = {}, acc10 = {}, acc11 = {}, accO0 = {}, accO1 = {};
    s8v ones;
#pragma unroll
    for (int j = 0; j < 8; ++j) ones[j] = (short)0x3F80;
    const int mrow = lane & 15, kq = (lane >> 4) * 8;

    for (int tile = 0; tile < 4; ++tile) {
        int go = tile * 128 + ss;
        us8 k0v = *(const us8*)(Kp + (size_t)sr * 4096 + go);
        us8 k1v = *(const us8*)(Kp + (size_t)sr * 4096 + go + 8);
        us8 v0v = *(const us8*)(Vp + (size_t)sr * 4096 + go);
        us8 v1v = *(const us8*)(Vp + (size_t)sr * 4096 + go + 8);
        __syncthreads();
        *(us8*)&Ks[sr * S + ss]     = k0v;
        *(us8*)&Ks[sr * S + ss + 8] = k1v;
        *(us8*)&Vs[sr * S + ss]     = v0v;
        *(us8*)&Vs[sr * S + ss + 8] = v1v;
        __syncthreads();
        int ko = wv * 32 + kq;
        s8v a0 = *(const s8v*)&Vs[(mrow)      * S + ko];
        s8v a1 = *(const s8v*)&Vs[(16 + mrow) * S + ko];
        s8v b0 = *(const s8v*)&Ks[(mrow)      * S + ko];
        s8v b1 = *(const s8v*)&Ks[(16 + mrow) * S + ko];
        acc00 = __builtin_amdgcn_mfma_f32_16x16x32_bf16(a0, b0, acc00, 0, 0, 0);
        acc01 = __builtin_amdgcn_mfma_f32_16x16x32_bf16(a0, b1, acc01, 0, 0, 0);
        acc10 = __builtin_amdgcn_mfma_f32_16x16x32_bf16(a1, b0, acc10, 0, 0, 0);
        acc11 = __builtin_amdgcn_mfma_f32_16x16x32_bf16(a1, b1, acc11, 0, 0, 0);
        accO0 = __builtin_amdgcn_mfma_f32_16x16x32_bf16(ones, b0, accO0, 0, 0, 0);
        accO1 = __builtin_amdgcn_mfma_f32_16x16x32_bf16(ones, b1, accO1, 0, 0, 0);
    }

    const int ccol = lane & 15, crow = (lane >> 4) * 4;
    float* R = Rs[wv];
#pragma unroll
    for (int r2 = 0; r2 < 4; ++r2) {
        R[(crow + r2) * 32 + ccol]           = acc00[r2];
        R[(crow + r2) * 32 + 16 + ccol]      = acc01[r2];
        R[(16 + crow + r2) * 32 + ccol]      = acc10[r2];
        R[(16 + crow + r2) * 32 + 16 + ccol] = acc11[r2];
    }
    if ((lane >> 4) == 0) {
        R[1024 + ccol]      = accO0[0];
        R[1024 + 16 + ccol] = accO1[0];
    }
    __syncthreads();
    float* vkb = vkws + bh * (33 * 32);
    for (int i = t; i < 1056; i += 256) {
        float s = Rs[0][i] + Rs[1][i] + Rs[2][i] + Rs[3][i];
        atomicAdd(&vkb[i], s);
    }
}

// --------------- y = (vk @ reluQ) / pad-row, MFMA K=32 ---------------------
__global__ __launch_bounds__(256)
void lite_apply(const unsigned short* __restrict__ qb,
                const float* __restrict__ vkws,
                unsigned short* __restrict__ yb) {
    const int bh = blockIdx.x, nb = blockIdx.y;
    const int b = bh >> 5, h = bh & 31;
    __shared__ unsigned short vkh[48 * 32];
    __shared__ unsigned short vkl[48 * 32];
    const int t = threadIdx.x;
    for (int i = t; i < 48 * 32; i += 256) {
        float v = (i < 33 * 32) ? vkws[bh * (33 * 32) + i] : 0.f;
        unsigned short hi = f2bf(v);
        vkh[i] = hi;
        vkl[i] = f2bf(v - bf2f(hi));
    }
    __syncthreads();

    const int lane = t & 63, wv = t >> 6;
    const int col = lane & 15, quad = lane >> 4;
    s8v b0h = *(const s8v*)&vkh[(col)      * 32 + quad * 8];
    s8v b0l = *(const s8v*)&vkl[(col)      * 32 + quad * 8];
    s8v b1h = *(const s8v*)&vkh[(16 + col) * 32 + quad * 8];
    s8v b1l = *(const s8v*)&vkl[(16 + col) * 32 + quad * 8];
    s8v b2h = *(const s8v*)&vkh[(32 + col) * 32 + quad * 8];
    s8v b2l = *(const s8v*)&vkl[(32 + col) * 32 + quad * 8];

    const int ntile = nb * 256 + wv * 64;
#pragma unroll
    for (int mi = 0; mi < 4; ++mi) {
        int tok = ntile + mi * 16 + col;
        const unsigned short* qp =
            qb + (size_t)(b * 4096 + tok) * 1024 + h * 32 + quad * 8;
        s8v a = *(const s8v*)qp;
        f32x4 n0 = {}, n1 = {}, dd = {};
        n0 = __builtin_amdgcn_mfma_f32_16x16x32_bf16(b0h, a, n0, 0, 0, 0);
        n0 = __builtin_amdgcn_mfma_f32_16x16x32_bf16(b0l, a, n0, 0, 0, 0);
        n1 = __builtin_amdgcn_mfma_f32_16x16x32_bf16(b1h, a, n1, 0, 0, 0);
        n1 = __builtin_amdgcn_mfma_f32_16x16x32_bf16(b1l, a, n1, 0, 0, 0);
        dd = __builtin_amdgcn_mfma_f32_16x16x32_bf16(b2h, a, dd, 0, 0, 0);
        dd = __builtin_amdgcn_mfma_f32_16x16x32_bf16(b2l, a, dd, 0, 0, 0);
        float den  = __shfl(dd[0], col, 64);
        float rinv = 1.f / (den + 1e-15f);
        us4 o0, o1;
#pragma unroll
        for (int r = 0; r < 4; ++r) {
            o0[r] = f2bf(n0[r] * rinv);
            o1[r] = f2bf(n1[r] * rinv);
        }
        size_t o = (size_t)(b * 4096 + tok) * 1024 + h * 32;
        *(us4*)&yb[o + quad * 4]      = o0;
        *(us4*)&yb[o + 16 + quad * 4] = o1;
    }
}

// ---------------------------------------------------------------------------
extern "C" void kernel_launch(void* const* d_in, const int* in_sizes, int n_in,
                              void* d_out, int out_size, void* d_ws, size_t ws_size,
                              hipStream_t stream) {
    const float* x     = (const float*)d_in[0];   // (4,4096,1024)
    const float* Wqkv  = (const float*)d_in[1];   // (3072,1024)
    const float* Wproj = (const float*)d_in[2];   // (1024,1024)
    const float* bproj = (const float*)d_in[3];   // (1024,)
    float* out = (float*)d_out;                   // (4,4096,1024) fp32

    const int M = 16384, Cdim = 1024, O1 = 3072;

    unsigned short* xb     = (unsigned short*)d_ws;
    unsigned short* wqkvb  = xb + (size_t)M * Cdim;
    unsigned short* wprojb = wqkvb + (size_t)O1 * Cdim;
    unsigned short* qb     = wprojb + (size_t)Cdim * Cdim;        // Q token-major
    unsigned short* kvT    = qb + (size_t)M * Cdim;               // [4][2048][4096]
    unsigned short* ybuf   = kvT + (size_t)4 * 2048 * 4096;
    float* vkws            = (float*)(ybuf + (size_t)M * Cdim);
    // ws use: ~176 MB

    static int attr_done = 0;
    if (!attr_done) {
        hipFuncSetAttribute((const void*)gemm_qkv,
                            hipFuncAttributeMaxDynamicSharedMemorySize, 98304);
        hipFuncSetAttribute((const void*)gemm_proj,
                            hipFuncAttributeMaxDynamicSharedMemorySize, 98304);
        attr_done = 1;
    }

    const int PREP_GROUPS = (16777216 + 3145728 + 1048576 + 135168) / 8;
    prep<<<(PREP_GROUPS + 255) / 256, 256, 0, stream>>>(
        x, Wqkv, Wproj, xb, wqkvb, wprojb, vkws);

    gemm_qkv<<<(M / 256) * (O1 / 256), 512, 98304, stream>>>(
        xb, wqkvb, qb, kvT, M, O1);

    lite_vk<<<dim3(128, 8), 256, 0, stream>>>(kvT, vkws);
    lite_apply<<<dim3(128, 16), 256, 0, stream>>>(qb, vkws, ybuf);

    gemm_proj<<<(M / 256) * (Cdim / 256), 512, 98304, stream>>>(
        ybuf, wprojb, out, bproj, M, Cdim);
}

// Round 6
// 339.372 us; speedup vs baseline: 1.0557x; 1.0557x over previous
//
#include <hip/hip_runtime.h>

// ---------------------------------------------------------------------------
// LiteMLA: B=4, N=4096, C=1024, D=32, h=32 heads.
//   qkv = x @ W_qkv^T            (16384 x 3072, K=1024)   [relu on q,k cols]
//   per (b,h): vk[d,e] = sum_n Vpad[d,n]*reluK[e,n]   (33x32, reduce N=4096)
//              y[d,n]  = (sum_e vk[d,e]*reluQ[e,n]) / (sum_e vk[32,e]*reluQ[e,n] + eps)
//   out = y @ W_proj^T + b_proj  (16384 x 1024, K=1024)
//
// GEMM (R6): R1-R5 all pinned at 34-40% MfmaUtil: with ONE resident block,
// per-phase barriers lockstep all waves -> LDS-read time (~2300cyc/tile) and
// MFMA time (~2480) SERIALIZE (measured 5500 cyc/tile = sum). Fix = overlap
// via INDEPENDENT blocks: 128x128 tile, 256 thr (4 waves, 64x64/wave,
// acc=64 VGPR), BK=32, triple-buffered A/B regions 8KB each -> 48 KiB LDS
// -> 3 blocks/CU (launch_bounds(256,3)); blocks share no barrier, so one
// block's MFMA overlaps another's reads/stage.
// Per K-tile (32 total): read 8 b128 frags ; stage tile g+2 (4 gload_lds) ;
// 16 MFMA ; vmcnt(4) ; barrier.  vmcnt(4) retires tile g+1's 4 loads
// (outstanding 8 -> keep 4 newest = g+2's); never drains 0. Prologue stages
// tiles 0,1 (8 loads), vmcnt(4) -> same steady state. Overwrite safety:
// buffer (g+2)%3 last read at tile g-1, drained by its barrier.
// LDS map (row-pair + XOR slot, DMA-linear dest / pre-swizzled source):
//   elem(row,k) at line=row>>1, slot=((row&1)*4+(k>>3))^(line&7),
//   off = line*64 + slot*8 + (k&7)   [verified element-exact; 2 lanes/slot
//   per kq-quarter = conflict-free]. Accumulation order per element
//   (k = 32g ascending) identical to all prior rounds -> same numerics.
// ---------------------------------------------------------------------------

using us8   = __attribute__((ext_vector_type(8))) unsigned short;
using us4   = __attribute__((ext_vector_type(4))) unsigned short;
using s8v   = __attribute__((ext_vector_type(8))) short;
using f32x4 = __attribute__((ext_vector_type(4))) float;

__device__ __forceinline__ unsigned short f2bf(float f) {
    union { float f; unsigned int u; } c; c.f = f;
    unsigned int r = c.u + 0x7fffu + ((c.u >> 16) & 1u);   // RTN-even
    return (unsigned short)(r >> 16);
}
__device__ __forceinline__ float bf2f(unsigned short u) {
    union { unsigned int u; float f; } c; c.u = ((unsigned int)u) << 16;
    return c.f;
}

// async global->LDS, 16B per lane; LDS dest = wave-uniform base + lane*16
__device__ __forceinline__ void async16(const unsigned short* g, unsigned short* l) {
    __builtin_amdgcn_global_load_lds(
        (const __attribute__((address_space(1))) unsigned int*)g,
        (__attribute__((address_space(3))) unsigned int*)l, 16, 0, 0);
}

// ------------------ fused fp32->bf16 converts + vkws zero ------------------
__global__ __launch_bounds__(256)
void prep(const float* __restrict__ x, const float* __restrict__ wq,
          const float* __restrict__ wp, unsigned short* __restrict__ xb,
          unsigned short* __restrict__ wqb, unsigned short* __restrict__ wpb,
          float* __restrict__ vkws) {
    const int NX = 16777216 / 8, NQ = 3145728 / 8, NP = 1048576 / 8, NZ = 135168 / 8;
    int gid = blockIdx.x * 256 + threadIdx.x;
    const float* in; unsigned short* out; int i;
    if (gid < NX)                    { in = x;  out = xb;  i = gid * 8; }
    else if (gid < NX + NQ)          { in = wq; out = wqb; i = (gid - NX) * 8; }
    else if (gid < NX + NQ + NP)     { in = wp; out = wpb; i = (gid - NX - NQ) * 8; }
    else if (gid < NX + NQ + NP + NZ) {
        int z = (gid - NX - NQ - NP) * 8;
        f32x4 zero = {};
        *(f32x4*)(vkws + z) = zero; *(f32x4*)(vkws + z + 4) = zero;
        return;
    } else return;
    float4 a = *(const float4*)(in + i);
    float4 b = *(const float4*)(in + i + 4);
    us8 o;
    o[0] = f2bf(a.x); o[1] = f2bf(a.y); o[2] = f2bf(a.z); o[3] = f2bf(a.w);
    o[4] = f2bf(b.x); o[5] = f2bf(b.y); o[6] = f2bf(b.z); o[7] = f2bf(b.w);
    *(us8*)(out + i) = o;
}

// ----------------- 128x128 / BK=32 / 3-blocks-per-CU GEMM ------------------
#define FENCE() asm volatile("" ::: "memory")
#define BARX()  do { FENCE(); __builtin_amdgcn_s_barrier(); FENCE(); } while (0)

// staging chunk decode: chunk c (16B) -> global elem offset (row*1024 + kq*8)
// matching the row-pair+XOR LDS map with a LINEAR DMA destination.
__device__ __forceinline__ int sdec(int c) {
    int line = c >> 3, slot = c & 7;
    int sraw = slot ^ (line & 7);
    return (line * 2 + (sraw >> 2)) * 1024 + (sraw & 3) * 8;
}

// MODE 0: cols<1024 -> Q token-major bf16 (relu); cols>=1024 -> kvT.
// MODE 1: fp32 + bias.
template <int MODE>
__device__ __forceinline__
void gemm_core128(const unsigned short* __restrict__ A,
                  const unsigned short* __restrict__ Bt,
                  unsigned short* __restrict__ Cq,
                  unsigned short* __restrict__ kvT,
                  float* __restrict__ Cf, const float* __restrict__ bias,
                  int N, int tM, int tN, unsigned short* lds) {
    unsigned short* As = lds;              // 3 regions x 4096 elems (8 KB)
    unsigned short* Bs = lds + 12288;      // 3 regions x 4096 elems

    const int t    = threadIdx.x;
    const int lane = t & 63;
    const int wv   = t >> 6;               // 4 waves
    const int wr   = wv >> 1;              // 0..1 : 64-row slab
    const int wc   = wv & 1;               // 0..1 : 64-col slab
    const int mrow = lane & 15;
    const int kq   = lane >> 4;            // 0..3

    // staging: thread t handles chunks t and 256+t of each region
    const int g0 = sdec(t), g1 = sdec(256 + t);
    const unsigned short* Ag0 = A  + (size_t)tM * 1024 + g0;
    const unsigned short* Ag1 = A  + (size_t)tM * 1024 + g1;
    const unsigned short* Bg0 = Bt + (size_t)tN * 1024 + g0;
    const unsigned short* Bg1 = Bt + (size_t)tN * 1024 + g1;
    const int dst0 = wv * 512, dst1 = 2048 + wv * 512;   // elems in region

    // frag read offsets (row-pair + XOR-slot map; slot invariant across mi)
    const int rA = wr * 64 + mrow, lA = rA >> 1;
    const int aoff = lA * 64 + ((((rA & 1) << 2) | kq) ^ (lA & 7)) * 8;
    const int rB = wc * 64 + mrow, lB = rB >> 1;
    const int boff = lB * 64 + ((((rB & 1) << 2) | kq) ^ (lB & 7)) * 8;

    f32x4 acc[4][4] = {};
    s8v af[4], bf[4];

    // prologue: stage tiles 0 and 1 (issue order [A0,A1,B0,B1] per tile)
    async16(Ag0, As + dst0);            async16(Ag1, As + dst1);
    async16(Bg0, Bs + dst0);            async16(Bg1, Bs + dst1);
    async16(Ag0 + 32, As + 4096 + dst0); async16(Ag1 + 32, As + 4096 + dst1);
    async16(Bg0 + 32, Bs + 4096 + dst0); async16(Bg1 + 32, Bs + 4096 + dst1);
    asm volatile("s_waitcnt vmcnt(4)" ::: "memory");   // tile0 landed
    BARX();

#pragma unroll
    for (int g = 0; g < 32; ++g) {
        const int rb = g % 3, sb = (g + 2) % 3;
        const int kt = (g + 2 < 32 ? g + 2 : 31) * 32;
        const unsigned short* Ar = As + rb * 4096;
        const unsigned short* Br = Bs + rb * 4096;
#pragma unroll
        for (int mi = 0; mi < 4; ++mi)
            af[mi] = *(const s8v*)&Ar[aoff + mi * 512];
#pragma unroll
        for (int ni = 0; ni < 4; ++ni)
            bf[ni] = *(const s8v*)&Br[boff + ni * 512];
        async16(Ag0 + kt, As + sb * 4096 + dst0);
        async16(Ag1 + kt, As + sb * 4096 + dst1);
        async16(Bg0 + kt, Bs + sb * 4096 + dst0);
        async16(Bg1 + kt, Bs + sb * 4096 + dst1);
        __builtin_amdgcn_s_setprio(1);
#pragma unroll
        for (int mi = 0; mi < 4; ++mi)
#pragma unroll
            for (int ni = 0; ni < 4; ++ni)
                acc[mi][ni] = __builtin_amdgcn_mfma_f32_16x16x32_bf16(
                    af[mi], bf[ni], acc[mi][ni], 0, 0, 0);
        __builtin_amdgcn_s_setprio(0);
        asm volatile("s_waitcnt vmcnt(4)" ::: "memory");  // tile g+1 landed
        BARX();
    }

    // ----------------------------- epilogue --------------------------------
    const int crow0 = kq * 4;
    if (MODE == 0) {
        if (tN >= 1024) {
            const int b2  = tM >> 12;
            const int nb0 = (tM & 4095) + wr * 64;
#pragma unroll
            for (int mi = 0; mi < 4; ++mi) {
                const int nbase = nb0 + mi * 16 + crow0;
#pragma unroll
                for (int ni = 0; ni < 4; ++ni) {
                    const int col = tN + wc * 64 + ni * 16 + mrow;
                    f32x4 v = acc[mi][ni];
                    if (col < 2048) {
                        v[0] = fmaxf(v[0], 0.f); v[1] = fmaxf(v[1], 0.f);
                        v[2] = fmaxf(v[2], 0.f); v[3] = fmaxf(v[3], 0.f);
                    }
                    us4 o;
                    o[0] = f2bf(v[0]); o[1] = f2bf(v[1]);
                    o[2] = f2bf(v[2]); o[3] = f2bf(v[3]);
                    *(us4*)&kvT[((size_t)b2 * 2048 + (col - 1024)) * 4096 + nbase] = o;
                }
            }
        } else {
#pragma unroll
            for (int mi = 0; mi < 4; ++mi)
#pragma unroll
                for (int ni = 0; ni < 4; ++ni) {
                    const int row = tM + wr * 64 + mi * 16 + crow0;
                    const int col = tN + wc * 64 + ni * 16 + mrow;
#pragma unroll
                    for (int r2 = 0; r2 < 4; ++r2)
                        Cq[(size_t)(row + r2) * 1024 + col] =
                            f2bf(fmaxf(acc[mi][ni][r2], 0.f));
                }
        }
    } else {
#pragma unroll
        for (int mi = 0; mi < 4; ++mi)
#pragma unroll
            for (int ni = 0; ni < 4; ++ni) {
                const int row = tM + wr * 64 + mi * 16 + crow0;
                const int col = tN + wc * 64 + ni * 16 + mrow;
#pragma unroll
                for (int r2 = 0; r2 < 4; ++r2)
                    Cf[(size_t)(row + r2) * N + col] = acc[mi][ni][r2] + bias[col];
            }
    }
    // drain LDS-DMA before wave exit (LDS may be re-allocated to next block)
    asm volatile("s_waitcnt vmcnt(0)" ::: "memory");
}

// XCD-aware tile map (128x128 tiles): xcd = blk&7 owns an M-stripe; N swept
// in panels of 4 (B-panel 1 MB stays L2-hot), tN fastest within panel.
__device__ __forceinline__ void xcd_map128(int blk, int MT, int& tM, int& tN) {
    const int xcd = blk & 7;
    const int i   = blk >> 3;
    const int MTx = MT >> 3;             // M-tiles per XCD (16)
    const int ppan = MTx * 4;            // blocks per 4-wide panel per XCD
    const int p   = i / ppan;
    const int i2  = i % ppan;
    tM = (xcd * MTx + (i2 >> 2)) * 128;
    tN = (p * 4 + (i2 & 3)) * 128;
}

__global__ __launch_bounds__(256, 3)
void gemm_qkv(const unsigned short* __restrict__ A,
              const unsigned short* __restrict__ Bt,
              unsigned short* __restrict__ Cq, unsigned short* __restrict__ kvT,
              int M, int N) {
    extern __shared__ unsigned short lds[];
    int tM, tN;
    xcd_map128(blockIdx.x, M >> 7, tM, tN);
    gemm_core128<0>(A, Bt, Cq, kvT, nullptr, nullptr, N, tM, tN, lds);
}

__global__ __launch_bounds__(256, 3)
void gemm_proj(const unsigned short* __restrict__ A,
               const unsigned short* __restrict__ Bt,
               float* __restrict__ C, const float* __restrict__ bias,
               int M, int N) {
    extern __shared__ unsigned short lds[];
    int tM, tN;
    xcd_map128(blockIdx.x, M >> 7, tM, tN);
    gemm_core128<1>(A, Bt, nullptr, nullptr, C, bias, N, tM, tN, lds);
}

// ---------------- vk = Vpad @ reluK^T via MFMA over kvT --------------------
__global__ __launch_bounds__(256)
void lite_vk(const unsigned short* __restrict__ kvT, float* __restrict__ vkws) {
    const int bh = blockIdx.x, ck = blockIdx.y;
    const int b = bh >> 5, h = bh & 31;
    const int S = 136;
    __shared__ unsigned short Ks[32 * S];
    __shared__ unsigned short Vs[32 * S];
    __shared__ float Rs[4][1088];
    const int t = threadIdx.x, lane = t & 63, wv = t >> 6;
    const unsigned short* Kp = kvT + ((size_t)b * 2048 + h * 32) * 4096 + ck * 512;
    const unsigned short* Vp = kvT + ((size_t)b * 2048 + 1024 + h * 32) * 4096 + ck * 512;
    const int sr = t >> 3, ss = (t & 7) * 16;
    f32x4 acc00 = {}, acc01 = {}, acc10 = {}, acc11 = {}, accO0 = {}, accO1 = {};
    s8v ones;
#pragma unroll
    for (int j = 0; j < 8; ++j) ones[j] = (short)0x3F80;
    const int mrow = lane & 15, kq = (lane >> 4) * 8;

    for (int tile = 0; tile < 4; ++tile) {
        int go = tile * 128 + ss;
        us8 k0v = *(const us8*)(Kp + (size_t)sr * 4096 + go);
        us8 k1v = *(const us8*)(Kp + (size_t)sr * 4096 + go + 8);
        us8 v0v = *(const us8*)(Vp + (size_t)sr * 4096 + go);
        us8 v1v = *(const us8*)(Vp + (size_t)sr * 4096 + go + 8);
        __syncthreads();
        *(us8*)&Ks[sr * S + ss]     = k0v;
        *(us8*)&Ks[sr * S + ss + 8] = k1v;
        *(us8*)&Vs[sr * S + ss]     = v0v;
        *(us8*)&Vs[sr * S + ss + 8] = v1v;
        __syncthreads();
        int ko = wv * 32 + kq;
        s8v a0 = *(const s8v*)&Vs[(mrow)      * S + ko];
        s8v a1 = *(const s8v*)&Vs[(16 + mrow) * S + ko];
        s8v b0 = *(const s8v*)&Ks[(mrow)      * S + ko];
        s8v b1 = *(const s8v*)&Ks[(16 + mrow) * S + ko];
        acc00 = __builtin_amdgcn_mfma_f32_16x16x32_bf16(a0, b0, acc00, 0, 0, 0);
        acc01 = __builtin_amdgcn_mfma_f32_16x16x32_bf16(a0, b1, acc01, 0, 0, 0);
        acc10 = __builtin_amdgcn_mfma_f32_16x16x32_bf16(a1, b0, acc10, 0, 0, 0);
        acc11 = __builtin_amdgcn_mfma_f32_16x16x32_bf16(a1, b1, acc11, 0, 0, 0);
        accO0 = __builtin_amdgcn_mfma_f32_16x16x32_bf16(ones, b0, accO0, 0, 0, 0);
        accO1 = __builtin_amdgcn_mfma_f32_16x16x32_bf16(ones, b1, accO1, 0, 0, 0);
    }

    const int ccol = lane & 15, crow = (lane >> 4) * 4;
    float* R = Rs[wv];
#pragma unroll
    for (int r2 = 0; r2 < 4; ++r2) {
        R[(crow + r2) * 32 + ccol]           = acc00[r2];
        R[(crow + r2) * 32 + 16 + ccol]      = acc01[r2];
        R[(16 + crow + r2) * 32 + ccol]      = acc10[r2];
        R[(16 + crow + r2) * 32 + 16 + ccol] = acc11[r2];
    }
    if ((lane >> 4) == 0) {
        R[1024 + ccol]      = accO0[0];
        R[1024 + 16 + ccol] = accO1[0];
    }
    __syncthreads();
    float* vkb = vkws + bh * (33 * 32);
    for (int i = t; i < 1056; i += 256) {
        float s = Rs[0][i] + Rs[1][i] + Rs[2][i] + Rs[3][i];
        atomicAdd(&vkb[i], s);
    }
}

// --------------- y = (vk @ reluQ) / pad-row, MFMA K=32 ---------------------
__global__ __launch_bounds__(256)
void lite_apply(const unsigned short* __restrict__ qb,
                const float* __restrict__ vkws,
                unsigned short* __restrict__ yb) {
    const int bh = blockIdx.x, nb = blockIdx.y;
    const int b = bh >> 5, h = bh & 31;
    __shared__ unsigned short vkh[48 * 32];
    __shared__ unsigned short vkl[48 * 32];
    const int t = threadIdx.x;
    for (int i = t; i < 48 * 32; i += 256) {
        float v = (i < 33 * 32) ? vkws[bh * (33 * 32) + i] : 0.f;
        unsigned short hi = f2bf(v);
        vkh[i] = hi;
        vkl[i] = f2bf(v - bf2f(hi));
    }
    __syncthreads();

    const int lane = t & 63, wv = t >> 6;
    const int col = lane & 15, quad = lane >> 4;
    s8v b0h = *(const s8v*)&vkh[(col)      * 32 + quad * 8];
    s8v b0l = *(const s8v*)&vkl[(col)      * 32 + quad * 8];
    s8v b1h = *(const s8v*)&vkh[(16 + col) * 32 + quad * 8];
    s8v b1l = *(const s8v*)&vkl[(16 + col) * 32 + quad * 8];
    s8v b2h = *(const s8v*)&vkh[(32 + col) * 32 + quad * 8];
    s8v b2l = *(const s8v*)&vkl[(32 + col) * 32 + quad * 8];

    const int ntile = nb * 256 + wv * 64;
#pragma unroll
    for (int mi = 0; mi < 4; ++mi) {
        int tok = ntile + mi * 16 + col;
        const unsigned short* qp =
            qb + (size_t)(b * 4096 + tok) * 1024 + h * 32 + quad * 8;
        s8v a = *(const s8v*)qp;
        f32x4 n0 = {}, n1 = {}, dd = {};
        n0 = __builtin_amdgcn_mfma_f32_16x16x32_bf16(b0h, a, n0, 0, 0, 0);
        n0 = __builtin_amdgcn_mfma_f32_16x16x32_bf16(b0l, a, n0, 0, 0, 0);
        n1 = __builtin_amdgcn_mfma_f32_16x16x32_bf16(b1h, a, n1, 0, 0, 0);
        n1 = __builtin_amdgcn_mfma_f32_16x16x32_bf16(b1l, a, n1, 0, 0, 0);
        dd = __builtin_amdgcn_mfma_f32_16x16x32_bf16(b2h, a, dd, 0, 0, 0);
        dd = __builtin_amdgcn_mfma_f32_16x16x32_bf16(b2l, a, dd, 0, 0, 0);
        float den  = __shfl(dd[0], col, 64);
        float rinv = 1.f / (den + 1e-15f);
        us4 o0, o1;
#pragma unroll
        for (int r = 0; r < 4; ++r) {
            o0[r] = f2bf(n0[r] * rinv);
            o1[r] = f2bf(n1[r] * rinv);
        }
        size_t o = (size_t)(b * 4096 + tok) * 1024 + h * 32;
        *(us4*)&yb[o + quad * 4]      = o0;
        *(us4*)&yb[o + 16 + quad * 4] = o1;
    }
}

// ---------------------------------------------------------------------------
extern "C" void kernel_launch(void* const* d_in, const int* in_sizes, int n_in,
                              void* d_out, int out_size, void* d_ws, size_t ws_size,
                              hipStream_t stream) {
    const float* x     = (const float*)d_in[0];   // (4,4096,1024)
    const float* Wqkv  = (const float*)d_in[1];   // (3072,1024)
    const float* Wproj = (const float*)d_in[2];   // (1024,1024)
    const float* bproj = (const float*)d_in[3];   // (1024,)
    float* out = (float*)d_out;                   // (4,4096,1024) fp32

    const int M = 16384, Cdim = 1024, O1 = 3072;

    unsigned short* xb     = (unsigned short*)d_ws;
    unsigned short* wqkvb  = xb + (size_t)M * Cdim;
    unsigned short* wprojb = wqkvb + (size_t)O1 * Cdim;
    unsigned short* qb     = wprojb + (size_t)Cdim * Cdim;        // Q token-major
    unsigned short* kvT    = qb + (size_t)M * Cdim;               // [4][2048][4096]
    unsigned short* ybuf   = kvT + (size_t)4 * 2048 * 4096;
    float* vkws            = (float*)(ybuf + (size_t)M * Cdim);
    // ws use: ~176 MB

    static int attr_done = 0;
    if (!attr_done) {
        hipFuncSetAttribute((const void*)gemm_qkv,
                            hipFuncAttributeMaxDynamicSharedMemorySize, 49152);
        hipFuncSetAttribute((const void*)gemm_proj,
                            hipFuncAttributeMaxDynamicSharedMemorySize, 49152);
        attr_done = 1;
    }

    const int PREP_GROUPS = (16777216 + 3145728 + 1048576 + 135168) / 8;
    prep<<<(PREP_GROUPS + 255) / 256, 256, 0, stream>>>(
        x, Wqkv, Wproj, xb, wqkvb, wprojb, vkws);

    gemm_qkv<<<(M / 128) * (O1 / 128), 256, 49152, stream>>>(
        xb, wqkvb, qb, kvT, M, O1);

    lite_vk<<<dim3(128, 8), 256, 0, stream>>>(kvT, vkws);
    lite_apply<<<dim3(128, 16), 256, 0, stream>>>(qb, vkws, ybuf);

    gemm_proj<<<(M / 128) * (Cdim / 128), 256, 49152, stream>>>(
        ybuf, wprojb, out, bproj, M, Cdim);
}

// Round 7
// 314.651 us; speedup vs baseline: 1.1387x; 1.0786x over previous
//
#include <hip/hip_runtime.h>

// ---------------------------------------------------------------------------
// LiteMLA: B=4, N=4096, C=1024, D=32, h=32 heads.
//   qkv = x @ W_qkv^T            (16384 x 3072, K=1024)   [relu on q,k cols]
//   per (b,h): vk[d,e] = sum_n Vpad[d,n]*reluK[e,n]   (33x32, reduce N=4096)
//              y[d,n]  = (sum_e vk[d,e]*reluQ[e,n]) / (sum_e vk[32,e]*reluQ[e,n] + eps)
//   out = y @ W_proj^T + b_proj  (16384 x 1024, K=1024)
//
// GEMM (R7): 256x256 tile, 8 waves (128x64/wave, R1's proven geometry/
// numerics), BK=32, LDS = 3 buffers x 32KB (A[256][32]+B[256][32]) = 96KB.
// R1-R6 post-mortem: per-tile LDS-port work (~2560cyc) and MFMA (~2060cyc)
// SERIALIZE because 4 barriers/tile lockstep all 8 waves into common
// read-vs-MFMA windows. Fix: ONE barrier + one vmcnt(4) per K-tile; between
// barriers waves drift a full tile, so one wave's MFMA burst overlaps
// another's ds_reads (port/pipe overlap without extra blocks; acc=128 VGPR
// pins 2 waves/SIMD so drift must come from sparse barriers).
// Per tile per wave: 12 ds_read_b128 (af x8, bf x4) ; stage tile g+2
// (4 async16 -> buf (g+2)%3) ; 32 MFMA (setprio) ; vmcnt(4) ; s_barrier.
// Safety: buf(g+2)%3 = buf(g-1)%3, readers drained at barrier(g-1); each
// wave's vmcnt(4) retires its stage(g+1) before barrier(g) -> all DMA for
// buf g+1 landed before any wave reads it; reads of tile g are register-
// consumed (compiler lgkm wait before MFMA) before barrier(g). vmcnt never
// drains to 0 in-loop. k ascends 0,32,... per element = R1's accumulation
// order -> bit-identical numerics.
// LDS map (K=32): elem(r,k) at r*32 + ((k>>3) ^ ((r>>1)&3))*8 + (k&7);
// lanes 0-7 hit bank-quads {0,4,1,5,2,6,3,7} (distinct), 2 lanes/quad per
// 16-lane group = free. DMA dest linear; source pre-swizzled (involution
// verified: read slot kq^s returns global quad kq).
// ---------------------------------------------------------------------------

using us8   = __attribute__((ext_vector_type(8))) unsigned short;
using us4   = __attribute__((ext_vector_type(4))) unsigned short;
using s8v   = __attribute__((ext_vector_type(8))) short;
using f32x4 = __attribute__((ext_vector_type(4))) float;

__device__ __forceinline__ unsigned short f2bf(float f) {
    union { float f; unsigned int u; } c; c.f = f;
    unsigned int r = c.u + 0x7fffu + ((c.u >> 16) & 1u);   // RTN-even
    return (unsigned short)(r >> 16);
}
__device__ __forceinline__ float bf2f(unsigned short u) {
    union { unsigned int u; float f; } c; c.u = ((unsigned int)u) << 16;
    return c.f;
}

// async global->LDS, 16B per lane; LDS dest = wave-uniform base + lane*16
__device__ __forceinline__ void async16(const unsigned short* g, unsigned short* l) {
    __builtin_amdgcn_global_load_lds(
        (const __attribute__((address_space(1))) unsigned int*)g,
        (__attribute__((address_space(3))) unsigned int*)l, 16, 0, 0);
}

// ------------------ fused fp32->bf16 converts + vkws zero ------------------
__global__ __launch_bounds__(256)
void prep(const float* __restrict__ x, const float* __restrict__ wq,
          const float* __restrict__ wp, unsigned short* __restrict__ xb,
          unsigned short* __restrict__ wqb, unsigned short* __restrict__ wpb,
          float* __restrict__ vkws) {
    const int NX = 16777216 / 8, NQ = 3145728 / 8, NP = 1048576 / 8, NZ = 135168 / 8;
    int gid = blockIdx.x * 256 + threadIdx.x;
    const float* in; unsigned short* out; int i;
    if (gid < NX)                    { in = x;  out = xb;  i = gid * 8; }
    else if (gid < NX + NQ)          { in = wq; out = wqb; i = (gid - NX) * 8; }
    else if (gid < NX + NQ + NP)     { in = wp; out = wpb; i = (gid - NX - NQ) * 8; }
    else if (gid < NX + NQ + NP + NZ) {
        int z = (gid - NX - NQ - NP) * 8;
        f32x4 zero = {};
        *(f32x4*)(vkws + z) = zero; *(f32x4*)(vkws + z + 4) = zero;
        return;
    } else return;
    float4 a = *(const float4*)(in + i);
    float4 b = *(const float4*)(in + i + 4);
    us8 o;
    o[0] = f2bf(a.x); o[1] = f2bf(a.y); o[2] = f2bf(a.z); o[3] = f2bf(a.w);
    o[4] = f2bf(b.x); o[5] = f2bf(b.y); o[6] = f2bf(b.z); o[7] = f2bf(b.w);
    *(us8*)(out + i) = o;
}

// --------------- 256x256 / BK=32 / sparse-barrier GEMM core ----------------
constexpr int TSZ = 16384;               // elems per buffer (A 8192 + B 8192)

#define FENCE() asm volatile("" ::: "memory")
#define BARX()  do { FENCE(); __builtin_amdgcn_s_barrier(); FENCE(); } while (0)

// stage one K-tile (A 256x32 + B 256x32) into buffer BS: 4 async16/thread.
// chunk c0 = t, c1 = 512+t of each operand half; source pre-swizzled.
#define STAGE(KT, BS)                                                        \
  do {                                                                       \
    async16(Ag + g0 + (KT), (BS) + d0);                                      \
    async16(Ag + g1 + (KT), (BS) + d1);                                      \
    async16(Bg + g0 + (KT), (BS) + 8192 + d0);                               \
    async16(Bg + g1 + (KT), (BS) + 8192 + d1);                               \
  } while (0)

// MODE 0: cols<1024 -> Q token-major bf16 (relu); cols>=1024 -> kvT.
// MODE 1: fp32 + bias.
template <int MODE>
__device__ __forceinline__
void gemm_core256(const unsigned short* __restrict__ A,
                  const unsigned short* __restrict__ Bt,
                  unsigned short* __restrict__ Cq,
                  unsigned short* __restrict__ kvT,
                  float* __restrict__ Cf, const float* __restrict__ bias,
                  int N, int tM, int tN, unsigned short* lds) {
    const int t    = threadIdx.x;
    const int lane = t & 63;
    const int wv   = t >> 6;
    const int wr   = wv >> 2;                 // 0..1 : A 128-row slab
    const int wc   = wv & 3;                  // 0..3 : 64-col slab
    const int mrow = lane & 15;
    const int kq   = lane >> 4;               // 0..3

    // staging decode: chunk c -> row r = c>>2, phys slot sp = c&3,
    // source k-quad = sp ^ ((r>>1)&3)  (involution with read swizzle)
    const int c0 = t, c1 = 512 + t;
    const int r0 = c0 >> 2, r1 = c1 >> 2;
    const int g0 = r0 * 1024 + ((c0 & 3) ^ ((r0 >> 1) & 3)) * 8;
    const int g1 = r1 * 1024 + ((c1 & 3) ^ ((r1 >> 1) & 3)) * 8;
    const unsigned short* Ag = A  + (size_t)tM * 1024;
    const unsigned short* Bg = Bt + (size_t)tN * 1024;
    const int d0 = wv * 512, d1 = 4096 + wv * 512;   // elems in operand half

    // ds_read offsets: swz invariant across mi/ni (base>>1 ≡ 0 mod 4)
    const int swz  = (kq ^ ((mrow >> 1) & 3)) * 8;
    const int aoff = (wr * 128 + mrow) * 32 + swz;    // + mi*512
    const int boff = (wc * 64  + mrow) * 32 + swz;    // + ni*512, +8192 base

    f32x4 acc[8][4] = {};
    s8v af[8], bf[4];

    constexpr int NT = 32;                    // K = 1024 = 32 x 32

    // prologue: tiles 0,1 -> buf0,buf1; vmcnt(4) retires tile0's 4 loads
    STAGE(0,  lds);
    STAGE(32, lds + TSZ);
    asm volatile("s_waitcnt vmcnt(4)" ::: "memory");
    BARX();

    unsigned short* bR = lds;                 // read  : tile g
    unsigned short* bT = lds + TSZ;           // ready : tile g+1
    unsigned short* bS = lds + 2 * TSZ;       // stage : tile g+2

    for (int g = 0; g < NT; ++g) {
        const int kt = (g + 2 < NT ? g + 2 : NT - 1) * 32;
#pragma unroll
        for (int mi = 0; mi < 8; ++mi)
            af[mi] = *(const s8v*)&bR[aoff + mi * 512];
#pragma unroll
        for (int ni = 0; ni < 4; ++ni)
            bf[ni] = *(const s8v*)&bR[8192 + boff + ni * 512];
        STAGE(kt, bS);
        __builtin_amdgcn_s_setprio(1);
#pragma unroll
        for (int mi = 0; mi < 8; ++mi)
#pragma unroll
            for (int ni = 0; ni < 4; ++ni)
                acc[mi][ni] = __builtin_amdgcn_mfma_f32_16x16x32_bf16(
                    af[mi], bf[ni], acc[mi][ni], 0, 0, 0);
        __builtin_amdgcn_s_setprio(0);
        asm volatile("s_waitcnt vmcnt(4)" ::: "memory");  // retire stage(g+1)
        BARX();
        unsigned short* tmp = bR; bR = bT; bT = bS; bS = tmp;
    }

    // ----------------------------- epilogue (R1-proven) --------------------
    const int crow0 = kq * 4;
    const int ccol  = mrow;
    if (MODE == 0) {
        if (tN >= 1024) {
            const int b2  = tM >> 12;
            const int nb0 = (tM & 4095) + wr * 128;
#pragma unroll
            for (int mi = 0; mi < 8; ++mi) {
                const int nbase = nb0 + mi * 16 + crow0;
#pragma unroll
                for (int ni = 0; ni < 4; ++ni) {
                    const int col = tN + wc * 64 + ni * 16 + ccol;
                    f32x4 v = acc[mi][ni];
                    if (col < 2048) {
                        v[0] = fmaxf(v[0], 0.f); v[1] = fmaxf(v[1], 0.f);
                        v[2] = fmaxf(v[2], 0.f); v[3] = fmaxf(v[3], 0.f);
                    }
                    us4 o;
                    o[0] = f2bf(v[0]); o[1] = f2bf(v[1]);
                    o[2] = f2bf(v[2]); o[3] = f2bf(v[3]);
                    *(us4*)&kvT[((size_t)b2 * 2048 + (col - 1024)) * 4096 + nbase] = o;
                }
            }
        } else {
#pragma unroll
            for (int mi = 0; mi < 8; ++mi)
#pragma unroll
                for (int ni = 0; ni < 4; ++ni) {
                    const int row = tM + wr * 128 + mi * 16 + crow0;
                    const int col = tN + wc * 64 + ni * 16 + ccol;
#pragma unroll
                    for (int r2 = 0; r2 < 4; ++r2)
                        Cq[(size_t)(row + r2) * 1024 + col] =
                            f2bf(fmaxf(acc[mi][ni][r2], 0.f));
                }
        }
    } else {
#pragma unroll
        for (int mi = 0; mi < 8; ++mi)
#pragma unroll
            for (int ni = 0; ni < 4; ++ni) {
                const int row = tM + wr * 128 + mi * 16 + crow0;
                const int col = tN + wc * 64 + ni * 16 + ccol;
#pragma unroll
                for (int r2 = 0; r2 < 4; ++r2)
                    Cf[(size_t)(row + r2) * N + col] = acc[mi][ni][r2] + bias[col];
            }
    }
    // drain LDS-DMA before wave exit (LDS may be re-allocated to next block)
    asm volatile("s_waitcnt vmcnt(0)" ::: "memory");
}

// XCD-aware tile map: xcd = blk&7 owns an 8-M-tile stripe; N swept in panels
// of 4 (B-panel 2 MB stays L2-hot), tN fastest within panel.
__device__ __forceinline__ void xcd_map256(int blk, int MT, int& tM, int& tN) {
    const int xcd = blk & 7;
    const int i   = blk >> 3;
    const int MTx = MT >> 3;             // M-tiles per XCD (8)
    const int ppan = MTx * 4;            // blocks per 4-wide panel per XCD
    const int p   = i / ppan;
    const int i2  = i % ppan;
    tM = (xcd * MTx + (i2 >> 2)) * 256;
    tN = (p * 4 + (i2 & 3)) * 256;
}

__global__ __launch_bounds__(512, 2)
void gemm_qkv(const unsigned short* __restrict__ A,
              const unsigned short* __restrict__ Bt,
              unsigned short* __restrict__ Cq, unsigned short* __restrict__ kvT,
              int M, int N) {
    extern __shared__ unsigned short lds[];
    int tM, tN;
    xcd_map256(blockIdx.x, M >> 8, tM, tN);
    gemm_core256<0>(A, Bt, Cq, kvT, nullptr, nullptr, N, tM, tN, lds);
}

__global__ __launch_bounds__(512, 2)
void gemm_proj(const unsigned short* __restrict__ A,
               const unsigned short* __restrict__ Bt,
               float* __restrict__ C, const float* __restrict__ bias,
               int M, int N) {
    extern __shared__ unsigned short lds[];
    int tM, tN;
    xcd_map256(blockIdx.x, M >> 8, tM, tN);
    gemm_core256<1>(A, Bt, nullptr, nullptr, C, bias, N, tM, tN, lds);
}

// ---------------- vk = Vpad @ reluK^T via MFMA over kvT --------------------
__global__ __launch_bounds__(256)
void lite_vk(const unsigned short* __restrict__ kvT, float* __restrict__ vkws) {
    const int bh = blockIdx.x, ck = blockIdx.y;
    const int b = bh >> 5, h = bh & 31;
    const int S = 136;
    __shared__ unsigned short Ks[32 * S];
    __shared__ unsigned short Vs[32 * S];
    __shared__ float Rs[4][1088];
    const int t = threadIdx.x, lane = t & 63, wv = t >> 6;
    const unsigned short* Kp = kvT + ((size_t)b * 2048 + h * 32) * 4096 + ck * 512;
    const unsigned short* Vp = kvT + ((size_t)b * 2048 + 1024 + h * 32) * 4096 + ck * 512;
    const int sr = t >> 3, ss = (t & 7) * 16;
    f32x4 acc00 = {}, acc01 = {}, acc10 = {}, acc11 = {}, accO0 = {}, accO1 = {};
    s8v ones;
#pragma unroll
    for (int j = 0; j < 8; ++j) ones[j] = (short)0x3F80;
    const int mrow = lane & 15, kq = (lane >> 4) * 8;

    for (int tile = 0; tile < 4; ++tile) {
        int go = tile * 128 + ss;
        us8 k0v = *(const us8*)(Kp + (size_t)sr * 4096 + go);
        us8 k1v = *(const us8*)(Kp + (size_t)sr * 4096 + go + 8);
        us8 v0v = *(const us8*)(Vp + (size_t)sr * 4096 + go);
        us8 v1v = *(const us8*)(Vp + (size_t)sr * 4096 + go + 8);
        __syncthreads();
        *(us8*)&Ks[sr * S + ss]     = k0v;
        *(us8*)&Ks[sr * S + ss + 8] = k1v;
        *(us8*)&Vs[sr * S + ss]     = v0v;
        *(us8*)&Vs[sr * S + ss + 8] = v1v;
        __syncthreads();
        int ko = wv * 32 + kq;
        s8v a0 = *(const s8v*)&Vs[(mrow)      * S + ko];
        s8v a1 = *(const s8v*)&Vs[(16 + mrow) * S + ko];
        s8v b0 = *(const s8v*)&Ks[(mrow)      * S + ko];
        s8v b1 = *(const s8v*)&Ks[(16 + mrow) * S + ko];
        acc00 = __builtin_amdgcn_mfma_f32_16x16x32_bf16(a0, b0, acc00, 0, 0, 0);
        acc01 = __builtin_amdgcn_mfma_f32_16x16x32_bf16(a0, b1, acc01, 0, 0, 0);
        acc10 = __builtin_amdgcn_mfma_f32_16x16x32_bf16(a1, b0, acc10, 0, 0, 0);
        acc11 = __builtin_amdgcn_mfma_f32_16x16x32_bf16(a1, b1, acc11, 0, 0, 0);
        accO0 = __builtin_amdgcn_mfma_f32_16x16x32_bf16(ones, b0, accO0, 0, 0, 0);
        accO1 = __builtin_amdgcn_mfma_f32_16x16x32_bf16(ones, b1, accO1, 0, 0, 0);
    }

    const int ccol = lane & 15, crow = (lane >> 4) * 4;
    float* R = Rs[wv];
#pragma unroll
    for (int r2 = 0; r2 < 4; ++r2) {
        R[(crow + r2) * 32 + ccol]           = acc00[r2];
        R[(crow + r2) * 32 + 16 + ccol]      = acc01[r2];
        R[(16 + crow + r2) * 32 + ccol]      = acc10[r2];
        R[(16 + crow + r2) * 32 + 16 + ccol] = acc11[r2];
    }
    if ((lane >> 4) == 0) {
        R[1024 + ccol]      = accO0[0];
        R[1024 + 16 + ccol] = accO1[0];
    }
    __syncthreads();
    float* vkb = vkws + bh * (33 * 32);
    for (int i = t; i < 1056; i += 256) {
        float s = Rs[0][i] + Rs[1][i] + Rs[2][i] + Rs[3][i];
        atomicAdd(&vkb[i], s);
    }
}

// --------------- y = (vk @ reluQ) / pad-row, MFMA K=32 ---------------------
__global__ __launch_bounds__(256)
void lite_apply(const unsigned short* __restrict__ qb,
                const float* __restrict__ vkws,
                unsigned short* __restrict__ yb) {
    const int bh = blockIdx.x, nb = blockIdx.y;
    const int b = bh >> 5, h = bh & 31;
    __shared__ unsigned short vkh[48 * 32];
    __shared__ unsigned short vkl[48 * 32];
    const int t = threadIdx.x;
    for (int i = t; i < 48 * 32; i += 256) {
        float v = (i < 33 * 32) ? vkws[bh * (33 * 32) + i] : 0.f;
        unsigned short hi = f2bf(v);
        vkh[i] = hi;
        vkl[i] = f2bf(v - bf2f(hi));
    }
    __syncthreads();

    const int lane = t & 63, wv = t >> 6;
    const int col = lane & 15, quad = lane >> 4;
    s8v b0h = *(const s8v*)&vkh[(col)      * 32 + quad * 8];
    s8v b0l = *(const s8v*)&vkl[(col)      * 32 + quad * 8];
    s8v b1h = *(const s8v*)&vkh[(16 + col) * 32 + quad * 8];
    s8v b1l = *(const s8v*)&vkl[(16 + col) * 32 + quad * 8];
    s8v b2h = *(const s8v*)&vkh[(32 + col) * 32 + quad * 8];
    s8v b2l = *(const s8v*)&vkl[(32 + col) * 32 + quad * 8];

    const int ntile = nb * 256 + wv * 64;
#pragma unroll
    for (int mi = 0; mi < 4; ++mi) {
        int tok = ntile + mi * 16 + col;
        const unsigned short* qp =
            qb + (size_t)(b * 4096 + tok) * 1024 + h * 32 + quad * 8;
        s8v a = *(const s8v*)qp;
        f32x4 n0 = {}, n1 = {}, dd = {};
        n0 = __builtin_amdgcn_mfma_f32_16x16x32_bf16(b0h, a, n0, 0, 0, 0);
        n0 = __builtin_amdgcn_mfma_f32_16x16x32_bf16(b0l, a, n0, 0, 0, 0);
        n1 = __builtin_amdgcn_mfma_f32_16x16x32_bf16(b1h, a, n1, 0, 0, 0);
        n1 = __builtin_amdgcn_mfma_f32_16x16x32_bf16(b1l, a, n1, 0, 0, 0);
        dd = __builtin_amdgcn_mfma_f32_16x16x32_bf16(b2h, a, dd, 0, 0, 0);
        dd = __builtin_amdgcn_mfma_f32_16x16x32_bf16(b2l, a, dd, 0, 0, 0);
        float den  = __shfl(dd[0], col, 64);
        float rinv = 1.f / (den + 1e-15f);
        us4 o0, o1;
#pragma unroll
        for (int r = 0; r < 4; ++r) {
            o0[r] = f2bf(n0[r] * rinv);
            o1[r] = f2bf(n1[r] * rinv);
        }
        size_t o = (size_t)(b * 4096 + tok) * 1024 + h * 32;
        *(us4*)&yb[o + quad * 4]      = o0;
        *(us4*)&yb[o + 16 + quad * 4] = o1;
    }
}

// ---------------------------------------------------------------------------
extern "C" void kernel_launch(void* const* d_in, const int* in_sizes, int n_in,
                              void* d_out, int out_size, void* d_ws, size_t ws_size,
                              hipStream_t stream) {
    const float* x     = (const float*)d_in[0];   // (4,4096,1024)
    const float* Wqkv  = (const float*)d_in[1];   // (3072,1024)
    const float* Wproj = (const float*)d_in[2];   // (1024,1024)
    const float* bproj = (const float*)d_in[3];   // (1024,)
    float* out = (float*)d_out;                   // (4,4096,1024) fp32

    const int M = 16384, Cdim = 1024, O1 = 3072;

    unsigned short* xb     = (unsigned short*)d_ws;
    unsigned short* wqkvb  = xb + (size_t)M * Cdim;
    unsigned short* wprojb = wqkvb + (size_t)O1 * Cdim;
    unsigned short* qb     = wprojb + (size_t)Cdim * Cdim;        // Q token-major
    unsigned short* kvT    = qb + (size_t)M * Cdim;               // [4][2048][4096]
    unsigned short* ybuf   = kvT + (size_t)4 * 2048 * 4096;
    float* vkws            = (float*)(ybuf + (size_t)M * Cdim);
    // ws use: ~176 MB

    static int attr_done = 0;
    if (!attr_done) {
        hipFuncSetAttribute((const void*)gemm_qkv,
                            hipFuncAttributeMaxDynamicSharedMemorySize, 98304);
        hipFuncSetAttribute((const void*)gemm_proj,
                            hipFuncAttributeMaxDynamicSharedMemorySize, 98304);
        attr_done = 1;
    }

    const int PREP_GROUPS = (16777216 + 3145728 + 1048576 + 135168) / 8;
    prep<<<(PREP_GROUPS + 255) / 256, 256, 0, stream>>>(
        x, Wqkv, Wproj, xb, wqkvb, wprojb, vkws);

    gemm_qkv<<<(M / 256) * (O1 / 256), 512, 98304, stream>>>(
        xb, wqkvb, qb, kvT, M, O1);

    lite_vk<<<dim3(128, 8), 256, 0, stream>>>(kvT, vkws);
    lite_apply<<<dim3(128, 16), 256, 0, stream>>>(qb, vkws, ybuf);

    gemm_proj<<<(M / 256) * (Cdim / 256), 512, 98304, stream>>>(
        ybuf, wprojb, out, bproj, M, Cdim);
}